// Round 1
// baseline (868.283 us; speedup 1.0000x reference)
//
#include <hip/hip_runtime.h>
#include <hip/hip_bf16.h>
#include <math.h>

#define B_    2
#define C_    192
#define H_    96
#define W_    96
#define HW_   (H_ * W_)          // 9216
#define NPIX_ (B_ * HW_)         // 18432
#define G_    12
#define CG_   16
#define KPTS_ 9
#define MLPH_ 384

// ---------------------------------------------------------------------------
// Kernel 1: per-pixel linear projections q,k,v -> qp,kp,vp (channels-last)
//   out[pix][d] = b[d] + sum_c X[b][c][hw] * W[c][d]
// thread = (pixel, 4 output channels). blockIdx.y selects q/k/v.
// ---------------------------------------------------------------------------
__global__ __launch_bounds__(256) void proj_kernel(
    const float* __restrict__ q, const float* __restrict__ k, const float* __restrict__ v,
    const float* __restrict__ Wq, const float* __restrict__ bq,
    const float* __restrict__ Wk, const float* __restrict__ bk,
    const float* __restrict__ Wv, const float* __restrict__ bv,
    float* __restrict__ qp, float* __restrict__ kp, float* __restrict__ vp)
{
    const int which = blockIdx.y;
    const float* X  = (which == 0) ? q  : (which == 1) ? k  : v;
    const float* Wm = (which == 0) ? Wq : (which == 1) ? Wk : Wv;
    const float* bb = (which == 0) ? bq : (which == 1) ? bk : bv;
    float*       O  = (which == 0) ? qp : (which == 1) ? kp : vp;

    const int idx = blockIdx.x * 256 + threadIdx.x;   // < NPIX_*48
    const int p   = idx / 48;
    const int d4  = (idx - p * 48) * 4;
    const int b   = p / HW_;
    const int hw  = p - b * HW_;
    const float* Xb = X + b * C_ * HW_ + hw;

    float4 acc = *(const float4*)(bb + d4);
    #pragma unroll 4
    for (int c = 0; c < C_; ++c) {
        const float  xv = Xb[c * HW_];
        const float4 wv = *(const float4*)(Wm + c * C_ + d4);
        acc.x = fmaf(xv, wv.x, acc.x);
        acc.y = fmaf(xv, wv.y, acc.y);
        acc.z = fmaf(xv, wv.z, acc.z);
        acc.w = fmaf(xv, wv.w, acc.w);
    }
    *(float4*)(O + p * C_ + d4) = acc;
}

// ---------------------------------------------------------------------------
// Kernel 2: deformable attention. 16 lanes handle one (pixel, group) pair;
// lane = channel within group (cg == hd == 16, head == group).
// ---------------------------------------------------------------------------
__global__ __launch_bounds__(256) void deform_attn_kernel(
    const float* __restrict__ qp, const float* __restrict__ kp,
    const float* __restrict__ vp, const float* __restrict__ offset,
    float* __restrict__ ao)
{
    const int tid    = threadIdx.x;
    const int lane_c = tid & 15;                       // channel in group
    const int pair   = blockIdx.x * 16 + (tid >> 4);   // (pixel, group) id
    const int g   = pair % G_;
    const int pix = pair / G_;                          // global pixel
    const int b   = pix / HW_;
    const int hw  = pix - b * HW_;
    const int h   = hw / W_;
    const int w   = hw - h * W_;

    const int gch = g * CG_ + lane_c;                  // channel in C
    const float qc = qp[pix * C_ + gch];

    // lanes 0..8 load (off_y, off_x) for their sample point
    float off_y = 0.f, off_x = 0.f;
    if (lane_c < KPTS_) {
        const int ob = ((b * (G_ * 2 * KPTS_)) + g * (2 * KPTS_) + lane_c * 2) * HW_ + hw;
        off_y = offset[ob];
        off_x = offset[ob + HW_];
    }

    const float* kp_b = kp + b * HW_ * C_;
    const float* vp_b = vp + b * HW_ * C_;

    float score[KPTS_];
    float vsamp[KPTS_];

    #pragma unroll
    for (int kk = 0; kk < KPTS_; ++kk) {
        const float oy = __shfl(off_y, kk, 16);
        const float ox = __shfl(off_x, kk, 16);
        const float py = (float)(h - 1 + kk / 3) + oy;
        const float px = (float)(w - 1 + kk % 3) + ox;
        const float fy = floorf(py), fx = floorf(px);
        const int   y0 = (int)fy,   x0 = (int)fx;
        const float wy1 = py - fy, wx1 = px - fx;
        const float wy0 = 1.f - wy1, wx0 = 1.f - wx1;

        float ks = 0.f, vs = 0.f;
        #define CORNER(yy, xx, wgt)                                        \
            if ((unsigned)(yy) < (unsigned)H_ && (unsigned)(xx) < (unsigned)W_) { \
                const int a = ((yy) * W_ + (xx)) * C_ + gch;               \
                ks = fmaf((wgt), kp_b[a], ks);                             \
                vs = fmaf((wgt), vp_b[a], vs);                             \
            }
        CORNER(y0,     x0,     wy0 * wx0)
        CORNER(y0,     x0 + 1, wy0 * wx1)
        CORNER(y0 + 1, x0,     wy1 * wx0)
        CORNER(y0 + 1, x0 + 1, wy1 * wx1)
        #undef CORNER

        float sc = qc * ks;
        sc += __shfl_xor(sc, 8, 16);
        sc += __shfl_xor(sc, 4, 16);
        sc += __shfl_xor(sc, 2, 16);
        sc += __shfl_xor(sc, 1, 16);
        score[kk] = sc * 0.25f;   // scale = hd^-0.5 = 1/4
        vsamp[kk] = vs;
    }

    // softmax over the 9 points (every lane has all scores)
    float m = score[0];
    #pragma unroll
    for (int kk = 1; kk < KPTS_; ++kk) m = fmaxf(m, score[kk]);
    float s = 0.f;
    #pragma unroll
    for (int kk = 0; kk < KPTS_; ++kk) { score[kk] = expf(score[kk] - m); s += score[kk]; }
    const float inv = 1.f / s;
    float oc = 0.f;
    #pragma unroll
    for (int kk = 0; kk < KPTS_; ++kk) oc = fmaf(score[kk], vsamp[kk], oc);

    ao[pix * C_ + gch] = oc * inv;
}

// ---------------------------------------------------------------------------
// Kernel 3: residual MLP. 16 pixels / block, LDS-staged x and h1 tiles.
// final[b][c][h][w] = x[c] + (gelu(x@W1+b1) @ W2 + b2)[c]
// ---------------------------------------------------------------------------
__global__ __launch_bounds__(256) void mlp_kernel(
    const float* __restrict__ ao,
    const float* __restrict__ W1, const float* __restrict__ b1,
    const float* __restrict__ W2, const float* __restrict__ b2,
    float* __restrict__ out)
{
    __shared__ float Xs[16][196];   // pad 192->196: 4-lane bank spread, 16B-aligned rows
    __shared__ float Hs[16][388];   // pad 384->388

    const int tid  = threadIdx.x;
    const int pix0 = blockIdx.x * 16;

    // stage X tile (16 x 192 floats) as float4
    for (int i = tid; i < 16 * 48; i += 256) {
        const int row = i / 48, col = i - row * 48;
        *(float4*)&Xs[row][col * 4] =
            ((const float4*)(ao + (pix0 + row) * C_))[col];
    }
    __syncthreads();

    const int p = tid >> 4;   // pixel in tile

    // ---- phase 1: h1 = gelu(x @ W1 + b1), 24 outputs/thread ----
    {
        const int j0 = (tid & 15) * 24;
        float acc[24];
        #pragma unroll
        for (int j = 0; j < 24; ++j) acc[j] = b1[j0 + j];
        #pragma unroll 2
        for (int c = 0; c < C_; ++c) {
            const float xv = Xs[p][c];
            #pragma unroll
            for (int jq = 0; jq < 6; ++jq) {
                const float4 wv = *(const float4*)(W1 + c * MLPH_ + j0 + jq * 4);
                acc[jq * 4 + 0] = fmaf(xv, wv.x, acc[jq * 4 + 0]);
                acc[jq * 4 + 1] = fmaf(xv, wv.y, acc[jq * 4 + 1]);
                acc[jq * 4 + 2] = fmaf(xv, wv.z, acc[jq * 4 + 2]);
                acc[jq * 4 + 3] = fmaf(xv, wv.w, acc[jq * 4 + 3]);
            }
        }
        #pragma unroll
        for (int j = 0; j < 24; ++j) {
            const float x = acc[j];
            Hs[p][j0 + j] = 0.5f * x * (1.f + erff(x * 0.70710678118f)); // exact GELU
        }
    }
    __syncthreads();

    // ---- phase 2: mlp = h1 @ W2 + b2; write residual sum, NCHW layout ----
    {
        const int d0 = (tid & 15) * 12;
        float acc[12];
        #pragma unroll
        for (int d = 0; d < 12; ++d) acc[d] = b2[d0 + d];
        #pragma unroll 2
        for (int c = 0; c < MLPH_; ++c) {
            const float hv = Hs[p][c];
            #pragma unroll
            for (int dq = 0; dq < 3; ++dq) {
                const float4 wv = *(const float4*)(W2 + c * C_ + d0 + dq * 4);
                acc[dq * 4 + 0] = fmaf(hv, wv.x, acc[dq * 4 + 0]);
                acc[dq * 4 + 1] = fmaf(hv, wv.y, acc[dq * 4 + 1]);
                acc[dq * 4 + 2] = fmaf(hv, wv.z, acc[dq * 4 + 2]);
                acc[dq * 4 + 3] = fmaf(hv, wv.w, acc[dq * 4 + 3]);
            }
        }
        const int pg = pix0 + p;
        const int b  = pg / HW_;
        const int hw = pg - b * HW_;
        float* ob = out + b * C_ * HW_ + hw;
        #pragma unroll
        for (int d = 0; d < 12; ++d)
            ob[(d0 + d) * HW_] = Xs[p][d0 + d] + acc[d];
    }
}

// ---------------------------------------------------------------------------
extern "C" void kernel_launch(void* const* d_in, const int* in_sizes, int n_in,
                              void* d_out, int out_size, void* d_ws, size_t ws_size,
                              hipStream_t stream)
{
    const float* q      = (const float*)d_in[0];
    const float* k      = (const float*)d_in[1];
    const float* v      = (const float*)d_in[2];
    const float* offset = (const float*)d_in[3];
    const float* Wq     = (const float*)d_in[4];
    const float* bq     = (const float*)d_in[5];
    const float* Wk     = (const float*)d_in[6];
    const float* bk     = (const float*)d_in[7];
    const float* Wv     = (const float*)d_in[8];
    const float* bv     = (const float*)d_in[9];
    const float* W1     = (const float*)d_in[10];
    const float* b1     = (const float*)d_in[11];
    const float* W2     = (const float*)d_in[12];
    const float* b2     = (const float*)d_in[13];

    float* ws = (float*)d_ws;
    float* qp = ws;
    float* kp = qp + NPIX_ * C_;
    float* vp = kp + NPIX_ * C_;
    float* ao = vp + NPIX_ * C_;   // attention output, channels-last [pix][C]

    dim3 pgrid(NPIX_ * 48 / 256, 3);
    proj_kernel<<<pgrid, 256, 0, stream>>>(q, k, v, Wq, bq, Wk, bk, Wv, bv, qp, kp, vp);

    deform_attn_kernel<<<NPIX_ * G_ / 16, 256, 0, stream>>>(qp, kp, vp, offset, ao);

    mlp_kernel<<<NPIX_ / 16, 256, 0, stream>>>(ao, W1, b1, W2, b2, (float*)d_out);
}

// Round 2
// 271.930 us; speedup vs baseline: 3.1930x; 3.1930x over previous
//
#include <hip/hip_runtime.h>
#include <hip/hip_bf16.h>
#include <math.h>

#define B_    2
#define C_    192
#define H_    96
#define W_    96
#define HW_   (H_ * W_)          // 9216
#define NPIX_ (B_ * HW_)         // 18432
#define G_    12
#define CG_   16
#define KPTS_ 9
#define MLPH_ 384

typedef __attribute__((ext_vector_type(8))) short s16x8;
typedef __attribute__((ext_vector_type(4))) float f32x4;

__device__ __forceinline__ ushort f2b(float f) {
    __hip_bfloat16 h = __float2bfloat16(f);
    return *reinterpret_cast<ushort*>(&h);
}

#define GLOAD16(gp, lp)                                                          \
    __builtin_amdgcn_global_load_lds(                                            \
        (const __attribute__((address_space(1))) void*)(gp),                     \
        (__attribute__((address_space(3))) void*)(lp), 16, 0, 0)

// ---------------------------------------------------------------------------
// pack: q/k/v NCHW fp32 -> channels-last bf16 Xcl[3][NPIX][192]
// grid (HW/64, B, 3)
// ---------------------------------------------------------------------------
__global__ __launch_bounds__(256) void pack_kernel(
    const float* __restrict__ q, const float* __restrict__ k,
    const float* __restrict__ v, ushort* __restrict__ Xcl)
{
    __shared__ ushort sm[64][200];   // row stride 400 B (16B-aligned, odd dword stride)
    const int t   = threadIdx.x;
    const int hw0 = blockIdx.x * 64;
    const int b   = blockIdx.y;
    const int z   = blockIdx.z;
    const float* X = (z == 0) ? q : (z == 1) ? k : v;

    const int hwl = t & 63;
    #pragma unroll 4
    for (int j = 0; j < 48; ++j) {
        const int c = (t >> 6) + j * 4;
        sm[hwl][c] = f2b(X[(b * C_ + c) * HW_ + hw0 + hwl]);
    }
    __syncthreads();
    #pragma unroll
    for (int jj = 0; jj < 6; ++jj) {
        const int idx = t + 256 * jj;        // < 64*24
        const int row = idx / 24, cq = idx - row * 24;
        const int pix = b * HW_ + hw0 + row;
        *(uint4*)&Xcl[((z * NPIX_) + pix) * C_ + cq * 8] = *(uint4*)&sm[row][cq * 8];
    }
}

// ---------------------------------------------------------------------------
// wpack: weights fp32 -> TRANSPOSED bf16 [N][K]:
//   WqT WkT WvT (192x192 each), W1T (384x192), W2T (192x384), contiguous.
// ---------------------------------------------------------------------------
__global__ __launch_bounds__(256) void wpack_kernel(
    const float* __restrict__ Wq, const float* __restrict__ Wk,
    const float* __restrict__ Wv, const float* __restrict__ W1,
    const float* __restrict__ W2, ushort* __restrict__ Wt)
{
    const int i = blockIdx.x * 256 + threadIdx.x;
    if (i < 110592) {                 // 3 x 192x192
        const int s = i / 36864, j = i - s * 36864;
        const float* src = (s == 0) ? Wq : (s == 1) ? Wk : Wv;
        const int d = j / 192, c = j - d * 192;
        Wt[i] = f2b(src[c * 192 + d]);
    } else if (i < 184320) {          // W1T [384][192]
        const int j = i - 110592, d = j / 192, c = j - d * 192;
        Wt[i] = f2b(W1[c * 384 + d]);
    } else if (i < 258048) {          // W2T [192][384]
        const int j = i - 184320, d = j / 384, c = j - d * 384;
        Wt[i] = f2b(W2[c * 192 + d]);
    }
}

// ---------------------------------------------------------------------------
// MFMA GEMM: O[M][N] = A[M][K] * BT[N][K]^T (+ epilogue)
//   BM=128 BN=64 BK=32, 4 waves (2m x 2n), 16x16x32 bf16 MFMA.
//   EPI 0: += bias, fp32 out (channels-last), blockIdx.z selects q/k/v
//   EPI 1: gelu(.+bias) -> bf16 out
//   EPI 2: .+bias+res -> NCHW fp32 out via LDS transpose
// LDS 16B chunks XOR-swizzled: chunk (r,s) holds global k-chunk s^((r>>1)&3)
// -> conflict-free-ish ds_read_b128 fragments; global_load_lds dest stays linear.
// ---------------------------------------------------------------------------
template<int KK>
__device__ __forceinline__ void stage_tiles(const ushort* Az, const ushort* Bz,
                                            ushort* dst, int t, int m0, int n0, int kt)
{
    const int r0 = t >> 2, s0 = t & 3;
    const int c0 = s0 ^ ((r0 >> 1) & 3);
    const int r1 = r0 + 64;
    const int c1 = s0 ^ ((r1 >> 1) & 3);
    GLOAD16(Az + (m0 + r0) * KK + kt * 32 + c0 * 8, dst + t * 8);
    GLOAD16(Az + (m0 + r1) * KK + kt * 32 + c1 * 8, dst + 2048 + t * 8);
    GLOAD16(Bz + (n0 + r0) * KK + kt * 32 + c0 * 8, dst + 4096 + t * 8);
}

template<int KK, int EPI>
__global__ __launch_bounds__(256) void gemm_kernel(
    const ushort* __restrict__ A,  const ushort* __restrict__ BT,
    const float* __restrict__ bias0, const float* __restrict__ bias1,
    const float* __restrict__ bias2,
    float* __restrict__ Of, ushort* __restrict__ Ob,
    const float* __restrict__ res, float* __restrict__ Onchw,
    int zAstr, int zBstr, int zOstr)
{
    constexpr int NKT = KK / 32;
    constexpr int LDS_SZ = (EPI == 2) ? (64 * 132 * 4) : 24576;  // >= 2*6144 ushorts
    __shared__ char lds_raw[LDS_SZ < 24576 ? 24576 : LDS_SZ];
    ushort* smem = (ushort*)lds_raw;

    const int t  = threadIdx.x;
    const int l  = t & 63;
    const int wid = t >> 6;
    const int wm = wid >> 1, wn = wid & 1;
    const int m0 = blockIdx.x * 128;
    const int n0 = blockIdx.y * 64;
    const int z  = blockIdx.z;
    const int Ntot = gridDim.y * 64;

    const ushort* Az = A  + (size_t)z * zAstr;
    const ushort* Bz = BT + (size_t)z * zBstr;
    const float* bias = (z == 0) ? bias0 : (z == 1) ? bias1 : bias2;

    // fragment LDS offsets (ushort units), fixed per thread
    int aoff[4], boff[2];
    #pragma unroll
    for (int f = 0; f < 4; ++f) {
        const int r = wm * 64 + f * 16 + (l & 15);
        const int s = (l >> 4) ^ ((r >> 1) & 3);
        aoff[f] = r * 32 + s * 8;
    }
    #pragma unroll
    for (int g = 0; g < 2; ++g) {
        const int r = wn * 32 + g * 16 + (l & 15);
        const int s = (l >> 4) ^ ((r >> 1) & 3);
        boff[g] = 4096 + r * 32 + s * 8;
    }

    f32x4 acc[4][2] = {};

    stage_tiles<KK>(Az, Bz, smem, t, m0, n0, 0);
    __syncthreads();

    for (int kt = 0; kt < NKT; ++kt) {
        const int cur = kt & 1;
        if (kt + 1 < NKT)
            stage_tiles<KK>(Az, Bz, smem + ((kt + 1) & 1) * 6144, t, m0, n0, kt + 1);

        const ushort* buf = smem + cur * 6144;
        s16x8 af[4], bf[2];
        #pragma unroll
        for (int f = 0; f < 4; ++f) af[f] = *(const s16x8*)(buf + aoff[f]);
        #pragma unroll
        for (int g = 0; g < 2; ++g) bf[g] = *(const s16x8*)(buf + boff[g]);
        #pragma unroll
        for (int f = 0; f < 4; ++f)
            #pragma unroll
            for (int g = 0; g < 2; ++g)
                acc[f][g] = __builtin_amdgcn_mfma_f32_16x16x32_bf16(af[f], bf[g], acc[f][g], 0, 0, 0);
        __syncthreads();
    }

    const int rowg = l >> 4, ncol = l & 15;
    float bv[2];
    #pragma unroll
    for (int g = 0; g < 2; ++g) bv[g] = bias[n0 + wn * 32 + g * 16 + ncol];

    if (EPI == 0) {
        float* O = Of + (size_t)z * zOstr;
        #pragma unroll
        for (int f = 0; f < 4; ++f)
            #pragma unroll
            for (int g = 0; g < 2; ++g)
                #pragma unroll
                for (int r = 0; r < 4; ++r) {
                    const int m = m0 + wm * 64 + f * 16 + rowg * 4 + r;
                    const int n = n0 + wn * 32 + g * 16 + ncol;
                    O[(size_t)m * Ntot + n] = acc[f][g][r] + bv[g];
                }
    } else if (EPI == 1) {
        #pragma unroll
        for (int f = 0; f < 4; ++f)
            #pragma unroll
            for (int g = 0; g < 2; ++g)
                #pragma unroll
                for (int r = 0; r < 4; ++r) {
                    const int m = m0 + wm * 64 + f * 16 + rowg * 4 + r;
                    const int n = n0 + wn * 32 + g * 16 + ncol;
                    const float x = acc[f][g][r] + bv[g];
                    Ob[(size_t)m * Ntot + n] = f2b(0.5f * x * (1.f + erff(x * 0.70710678118f)));
                }
    } else {
        // EPI 2: stage (acc+bias+res) transposed in LDS, then coalesced NCHW store
        float* tsp = (float*)lds_raw;   // [64][132]
        #pragma unroll
        for (int f = 0; f < 4; ++f)
            #pragma unroll
            for (int g = 0; g < 2; ++g)
                #pragma unroll
                for (int r = 0; r < 4; ++r) {
                    const int ml = wm * 64 + f * 16 + rowg * 4 + r;
                    const int nl = wn * 32 + g * 16 + ncol;
                    const float rv = res[(size_t)(m0 + ml) * C_ + n0 + nl];
                    tsp[nl * 132 + ml] = acc[f][g][r] + bv[g] + rv;
                }
        __syncthreads();
        const int b   = m0 / HW_;
        const int hw0 = m0 - b * HW_;
        #pragma unroll
        for (int jj = 0; jj < 8; ++jj) {
            const int i4 = t + 256 * jj;      // < 64*32
            const int nn = i4 >> 5, mc = i4 & 31;
            float4 val = *(float4*)&tsp[nn * 132 + mc * 4];
            *(float4*)&Onchw[(size_t)b * C_ * HW_ + (size_t)(n0 + nn) * HW_ + hw0 + mc * 4] = val;
        }
    }
}

// ---------------------------------------------------------------------------
// deformable attention (unchanged math); also emits bf16 copy for MLP GEMM A.
// ---------------------------------------------------------------------------
__global__ __launch_bounds__(256) void deform_attn_kernel(
    const float* __restrict__ qp, const float* __restrict__ kp,
    const float* __restrict__ vp, const float* __restrict__ offset,
    float* __restrict__ ao, ushort* __restrict__ aob)
{
    const int tid    = threadIdx.x;
    const int lane_c = tid & 15;
    const int pair   = blockIdx.x * 16 + (tid >> 4);
    const int g   = pair % G_;
    const int pix = pair / G_;
    const int b   = pix / HW_;
    const int hw  = pix - b * HW_;
    const int h   = hw / W_;
    const int w   = hw - h * W_;

    const int gch = g * CG_ + lane_c;
    const float qc = qp[pix * C_ + gch];

    float off_y = 0.f, off_x = 0.f;
    if (lane_c < KPTS_) {
        const int ob = ((b * (G_ * 2 * KPTS_)) + g * (2 * KPTS_) + lane_c * 2) * HW_ + hw;
        off_y = offset[ob];
        off_x = offset[ob + HW_];
    }

    const float* kp_b = kp + b * HW_ * C_;
    const float* vp_b = vp + b * HW_ * C_;

    float score[KPTS_];
    float vsamp[KPTS_];

    #pragma unroll
    for (int kk = 0; kk < KPTS_; ++kk) {
        const float oy = __shfl(off_y, kk, 16);
        const float ox = __shfl(off_x, kk, 16);
        const float py = (float)(h - 1 + kk / 3) + oy;
        const float px = (float)(w - 1 + kk % 3) + ox;
        const float fy = floorf(py), fx = floorf(px);
        const int   y0 = (int)fy,   x0 = (int)fx;
        const float wy1 = py - fy, wx1 = px - fx;
        const float wy0 = 1.f - wy1, wx0 = 1.f - wx1;

        float ks = 0.f, vs = 0.f;
        #define CORNER(yy, xx, wgt)                                        \
            if ((unsigned)(yy) < (unsigned)H_ && (unsigned)(xx) < (unsigned)W_) { \
                const int a = ((yy) * W_ + (xx)) * C_ + gch;               \
                ks = fmaf((wgt), kp_b[a], ks);                             \
                vs = fmaf((wgt), vp_b[a], vs);                             \
            }
        CORNER(y0,     x0,     wy0 * wx0)
        CORNER(y0,     x0 + 1, wy0 * wx1)
        CORNER(y0 + 1, x0,     wy1 * wx0)
        CORNER(y0 + 1, x0 + 1, wy1 * wx1)
        #undef CORNER

        float sc = qc * ks;
        sc += __shfl_xor(sc, 8, 16);
        sc += __shfl_xor(sc, 4, 16);
        sc += __shfl_xor(sc, 2, 16);
        sc += __shfl_xor(sc, 1, 16);
        score[kk] = sc * 0.25f;
        vsamp[kk] = vs;
    }

    float m = score[0];
    #pragma unroll
    for (int kk = 1; kk < KPTS_; ++kk) m = fmaxf(m, score[kk]);
    float s = 0.f;
    #pragma unroll
    for (int kk = 0; kk < KPTS_; ++kk) { score[kk] = expf(score[kk] - m); s += score[kk]; }
    const float inv = 1.f / s;
    float oc = 0.f;
    #pragma unroll
    for (int kk = 0; kk < KPTS_; ++kk) oc = fmaf(score[kk], vsamp[kk], oc);
    oc *= inv;

    ao[pix * C_ + gch]  = oc;
    aob[pix * C_ + gch] = f2b(oc);
}

// ---------------------------------------------------------------------------
extern "C" void kernel_launch(void* const* d_in, const int* in_sizes, int n_in,
                              void* d_out, int out_size, void* d_ws, size_t ws_size,
                              hipStream_t stream)
{
    const float* q      = (const float*)d_in[0];
    const float* k      = (const float*)d_in[1];
    const float* v      = (const float*)d_in[2];
    const float* offset = (const float*)d_in[3];
    const float* Wq     = (const float*)d_in[4];
    const float* bq     = (const float*)d_in[5];
    const float* Wk     = (const float*)d_in[6];
    const float* bk     = (const float*)d_in[7];
    const float* Wv     = (const float*)d_in[8];
    const float* bv     = (const float*)d_in[9];
    const float* W1     = (const float*)d_in[10];
    const float* b1     = (const float*)d_in[11];
    const float* W2     = (const float*)d_in[12];
    const float* b2     = (const float*)d_in[13];

    float* ws = (float*)d_ws;
    float* qp = ws;                        // [NPIX][192] fp32
    float* kp = qp + NPIX_ * C_;
    float* vp = kp + NPIX_ * C_;
    float* ao = vp + NPIX_ * C_;           // attention out fp32 (residual)
    ushort* Xcl = (ushort*)(ao + NPIX_ * C_);   // [3][NPIX][192] bf16
    ushort* aob = Xcl;                          // alias (Xcl dead after proj)
    ushort* Hb  = Xcl + NPIX_ * C_;             // [NPIX][384] bf16
    ushort* Wt  = Xcl + 3 * NPIX_ * C_;         // transposed bf16 weights
    ushort* W1T = Wt + 110592;
    ushort* W2T = Wt + 184320;

    pack_kernel<<<dim3(HW_ / 64, B_, 3), 256, 0, stream>>>(q, k, v, Xcl);
    wpack_kernel<<<1008, 256, 0, stream>>>(Wq, Wk, Wv, W1, W2, Wt);

    // q/k/v projections: z selects matrix; outputs qp,kp,vp (channels-last fp32)
    gemm_kernel<192, 0><<<dim3(NPIX_ / 128, 3, 3), 256, 0, stream>>>(
        Xcl, Wt, bq, bk, bv, qp, nullptr, nullptr, nullptr,
        NPIX_ * C_, C_ * C_, NPIX_ * C_);

    deform_attn_kernel<<<NPIX_ * G_ / 16, 256, 0, stream>>>(qp, kp, vp, offset, ao, aob);

    // MLP1: H = gelu(ao @ W1 + b1), bf16
    gemm_kernel<192, 1><<<dim3(NPIX_ / 128, 6, 1), 256, 0, stream>>>(
        aob, W1T, b1, b1, b1, nullptr, Hb, nullptr, nullptr, 0, 0, 0);

    // MLP2: out = ao + (H @ W2 + b2), NCHW fp32
    gemm_kernel<384, 2><<<dim3(NPIX_ / 128, 3, 1), 256, 0, stream>>>(
        Hb, W2T, b2, b2, b2, nullptr, nullptr, ao, (float*)d_out, 0, 0, 0);
}

// Round 3
// 216.398 us; speedup vs baseline: 4.0124x; 1.2566x over previous
//
#include <hip/hip_runtime.h>
#include <hip/hip_bf16.h>
#include <math.h>

#define B_    2
#define C_    192
#define H_    96
#define W_    96
#define HW_   (H_ * W_)          // 9216
#define NPIX_ (B_ * HW_)         // 18432
#define G_    12
#define CG_   16
#define KPTS_ 9
#define MLPH_ 384

typedef __attribute__((ext_vector_type(8))) short s16x8;
typedef __attribute__((ext_vector_type(4))) float f32x4;

__device__ __forceinline__ ushort f2b(float f) {
    __hip_bfloat16 h = __float2bfloat16(f);
    return *reinterpret_cast<ushort*>(&h);
}
__device__ __forceinline__ float b2f(ushort u) {
    return __uint_as_float(((uint)u) << 16);
}
__device__ __forceinline__ float b2f_lo(uint u) { return __uint_as_float(u << 16); }
__device__ __forceinline__ float b2f_hi(uint u) { return __uint_as_float(u & 0xffff0000u); }

#define GLOAD16(gp, lp)                                                          \
    __builtin_amdgcn_global_load_lds(                                            \
        (const __attribute__((address_space(1))) void*)(gp),                     \
        (__attribute__((address_space(3))) void*)(lp), 16, 0, 0)

// ---------------------------------------------------------------------------
// pack: q/k/v NCHW fp32 -> channels-last bf16 Xcl[3][NPIX][192]
// ---------------------------------------------------------------------------
__global__ __launch_bounds__(256) void pack_kernel(
    const float* __restrict__ q, const float* __restrict__ k,
    const float* __restrict__ v, ushort* __restrict__ Xcl)
{
    __shared__ ushort sm[64][200];
    const int t   = threadIdx.x;
    const int hw0 = blockIdx.x * 64;
    const int b   = blockIdx.y;
    const int z   = blockIdx.z;
    const float* X = (z == 0) ? q : (z == 1) ? k : v;

    const int hwl = t & 63;
    #pragma unroll 4
    for (int j = 0; j < 48; ++j) {
        const int c = (t >> 6) + j * 4;
        sm[hwl][c] = f2b(X[(b * C_ + c) * HW_ + hw0 + hwl]);
    }
    __syncthreads();
    #pragma unroll
    for (int jj = 0; jj < 6; ++jj) {
        const int idx = t + 256 * jj;
        const int row = idx / 24, cq = idx - row * 24;
        const int pix = b * HW_ + hw0 + row;
        *(uint4*)&Xcl[((z * NPIX_) + pix) * C_ + cq * 8] = *(uint4*)&sm[row][cq * 8];
    }
}

// ---------------------------------------------------------------------------
// wpack: weights fp32 -> TRANSPOSED bf16 [N][K]
// ---------------------------------------------------------------------------
__global__ __launch_bounds__(256) void wpack_kernel(
    const float* __restrict__ Wq, const float* __restrict__ Wk,
    const float* __restrict__ Wv, const float* __restrict__ W1,
    const float* __restrict__ W2, ushort* __restrict__ Wt)
{
    const int i = blockIdx.x * 256 + threadIdx.x;
    if (i < 110592) {
        const int s = i / 36864, j = i - s * 36864;
        const float* src = (s == 0) ? Wq : (s == 1) ? Wk : Wv;
        const int d = j / 192, c = j - d * 192;
        Wt[i] = f2b(src[c * 192 + d]);
    } else if (i < 184320) {
        const int j = i - 110592, d = j / 192, c = j - d * 192;
        Wt[i] = f2b(W1[c * 384 + d]);
    } else if (i < 258048) {
        const int j = i - 184320, d = j / 384, c = j - d * 384;
        Wt[i] = f2b(W2[c * 192 + d]);
    }
}

// ---------------------------------------------------------------------------
// MFMA GEMM: O[M][N] = A[M][K] * BT[N][K]^T (+ epilogue)
//   EPI 0: bias -> bf16 channels-last (z selects q/k/v)
//   EPI 1: gelu(.+bias) -> bf16
//   EPI 2: .+bias+res(bf16) -> NCHW fp32 via LDS transpose
// ---------------------------------------------------------------------------
template<int KK>
__device__ __forceinline__ void stage_tiles(const ushort* Az, const ushort* Bz,
                                            ushort* dst, int t, int m0, int n0, int kt)
{
    const int r0 = t >> 2, s0 = t & 3;
    const int c0 = s0 ^ ((r0 >> 1) & 3);
    const int r1 = r0 + 64;
    const int c1 = s0 ^ ((r1 >> 1) & 3);
    GLOAD16(Az + (m0 + r0) * KK + kt * 32 + c0 * 8, dst + t * 8);
    GLOAD16(Az + (m0 + r1) * KK + kt * 32 + c1 * 8, dst + 2048 + t * 8);
    GLOAD16(Bz + (n0 + r0) * KK + kt * 32 + c0 * 8, dst + 4096 + t * 8);
}

template<int KK, int EPI>
__global__ __launch_bounds__(256) void gemm_kernel(
    const ushort* __restrict__ A,  const ushort* __restrict__ BT,
    const float* __restrict__ bias0, const float* __restrict__ bias1,
    const float* __restrict__ bias2,
    ushort* __restrict__ Ob,
    const ushort* __restrict__ res, float* __restrict__ Onchw,
    int zAstr, int zBstr, int zOstr)
{
    constexpr int LDS_SZ = (EPI == 2) ? (64 * 132 * 4) : 24576;
    __shared__ char lds_raw[LDS_SZ < 24576 ? 24576 : LDS_SZ];
    ushort* smem = (ushort*)lds_raw;

    const int t  = threadIdx.x;
    const int l  = t & 63;
    const int wid = t >> 6;
    const int wm = wid >> 1, wn = wid & 1;
    const int m0 = blockIdx.x * 128;
    const int n0 = blockIdx.y * 64;
    const int z  = blockIdx.z;
    const int Ntot = gridDim.y * 64;
    constexpr int NKT = KK / 32;

    const ushort* Az = A  + (size_t)z * zAstr;
    const ushort* Bz = BT + (size_t)z * zBstr;
    const float* bias = (z == 0) ? bias0 : (z == 1) ? bias1 : bias2;

    int aoff[4], boff[2];
    #pragma unroll
    for (int f = 0; f < 4; ++f) {
        const int r = wm * 64 + f * 16 + (l & 15);
        const int s = (l >> 4) ^ ((r >> 1) & 3);
        aoff[f] = r * 32 + s * 8;
    }
    #pragma unroll
    for (int g = 0; g < 2; ++g) {
        const int r = wn * 32 + g * 16 + (l & 15);
        const int s = (l >> 4) ^ ((r >> 1) & 3);
        boff[g] = 4096 + r * 32 + s * 8;
    }

    f32x4 acc[4][2] = {};

    stage_tiles<KK>(Az, Bz, smem, t, m0, n0, 0);
    __syncthreads();

    for (int kt = 0; kt < NKT; ++kt) {
        const int cur = kt & 1;
        if (kt + 1 < NKT)
            stage_tiles<KK>(Az, Bz, smem + ((kt + 1) & 1) * 6144, t, m0, n0, kt + 1);

        const ushort* buf = smem + cur * 6144;
        s16x8 af[4], bf[2];
        #pragma unroll
        for (int f = 0; f < 4; ++f) af[f] = *(const s16x8*)(buf + aoff[f]);
        #pragma unroll
        for (int g = 0; g < 2; ++g) bf[g] = *(const s16x8*)(buf + boff[g]);
        #pragma unroll
        for (int f = 0; f < 4; ++f)
            #pragma unroll
            for (int g = 0; g < 2; ++g)
                acc[f][g] = __builtin_amdgcn_mfma_f32_16x16x32_bf16(af[f], bf[g], acc[f][g], 0, 0, 0);
        __syncthreads();
    }

    const int rowg = l >> 4, ncol = l & 15;
    float bv[2];
    #pragma unroll
    for (int g = 0; g < 2; ++g) bv[g] = bias[n0 + wn * 32 + g * 16 + ncol];

    if (EPI == 0) {
        ushort* O = Ob + (size_t)z * zOstr;
        #pragma unroll
        for (int f = 0; f < 4; ++f)
            #pragma unroll
            for (int g = 0; g < 2; ++g)
                #pragma unroll
                for (int r = 0; r < 4; ++r) {
                    const int m = m0 + wm * 64 + f * 16 + rowg * 4 + r;
                    const int n = n0 + wn * 32 + g * 16 + ncol;
                    O[(size_t)m * Ntot + n] = f2b(acc[f][g][r] + bv[g]);
                }
    } else if (EPI == 1) {
        #pragma unroll
        for (int f = 0; f < 4; ++f)
            #pragma unroll
            for (int g = 0; g < 2; ++g)
                #pragma unroll
                for (int r = 0; r < 4; ++r) {
                    const int m = m0 + wm * 64 + f * 16 + rowg * 4 + r;
                    const int n = n0 + wn * 32 + g * 16 + ncol;
                    const float x = acc[f][g][r] + bv[g];
                    Ob[(size_t)m * Ntot + n] = f2b(0.5f * x * (1.f + erff(x * 0.70710678118f)));
                }
    } else {
        float* tsp = (float*)lds_raw;   // [64][132]
        #pragma unroll
        for (int f = 0; f < 4; ++f)
            #pragma unroll
            for (int g = 0; g < 2; ++g)
                #pragma unroll
                for (int r = 0; r < 4; ++r) {
                    const int ml = wm * 64 + f * 16 + rowg * 4 + r;
                    const int nl = wn * 32 + g * 16 + ncol;
                    const float rv = b2f(res[(size_t)(m0 + ml) * C_ + n0 + nl]);
                    tsp[nl * 132 + ml] = acc[f][g][r] + bv[g] + rv;
                }
        __syncthreads();
        const int b   = m0 / HW_;
        const int hw0 = m0 - b * HW_;
        #pragma unroll
        for (int jj = 0; jj < 8; ++jj) {
            const int i4 = t + 256 * jj;
            const int nn = i4 >> 5, mc = i4 & 31;
            float4 val = *(float4*)&tsp[nn * 132 + mc * 4];
            *(float4*)&Onchw[(size_t)b * C_ * HW_ + (size_t)(n0 + nn) * HW_ + hw0 + mc * 4] = val;
        }
    }
}

// ---------------------------------------------------------------------------
// deformable attention v2: 4 lanes per (pixel, group); lane owns 4 channels.
// bf16 gathers, XCD-swizzled blocks for L2 locality, bf16 output.
// ---------------------------------------------------------------------------
__global__ __launch_bounds__(256, 4) void deform_attn_kernel(
    const ushort* __restrict__ qp, const ushort* __restrict__ kp,
    const ushort* __restrict__ vp, const float* __restrict__ offset,
    ushort* __restrict__ aob)
{
    const int t   = threadIdx.x;
    const int bid = blockIdx.x;                    // 3456 blocks
    const int xb  = (bid & 7) * 432 + (bid >> 3);  // XCD-chunked swizzle
    const int pair = xb * 64 + (t >> 2);
    const int lane4 = t & 3;
    const int g   = pair % G_;
    const int pix = pair / G_;
    const int b   = pix / HW_;
    const int hw  = pix - b * HW_;
    const int h   = hw / W_;
    const int w   = hw - h * W_;
    const int gc0 = g * CG_ + lane4 * 4;

    // q: 4 channels
    float q0, q1, q2, q3;
    {
        uint2 qu = *(const uint2*)(qp + pix * C_ + gc0);
        q0 = b2f_lo(qu.x); q1 = b2f_hi(qu.x);
        q2 = b2f_lo(qu.y); q3 = b2f_hi(qu.y);
    }

    // offsets: lane l preloads points l, l+4, l+8
    float offy[3] = {0.f, 0.f, 0.f}, offx[3] = {0.f, 0.f, 0.f};
    {
        const int obase = (b * (G_ * 2 * KPTS_) + g * (2 * KPTS_)) * HW_ + hw;
        #pragma unroll
        for (int s = 0; s < 3; ++s) {
            const int kk = lane4 + s * 4;
            if (kk < KPTS_) {
                offy[s] = offset[obase + (kk * 2) * HW_];
                offx[s] = offset[obase + (kk * 2 + 1) * HW_];
            }
        }
    }

    const ushort* kp_b = kp + (size_t)b * HW_ * C_;
    const ushort* vp_b = vp + (size_t)b * HW_ * C_;

    float score[KPTS_];
    f32x4 vsamp[KPTS_];

    #pragma unroll
    for (int kk = 0; kk < KPTS_; ++kk) {
        const float oy = __shfl(offy[kk >> 2], kk & 3, 4);
        const float ox = __shfl(offx[kk >> 2], kk & 3, 4);
        const float py = (float)(h - 1 + kk / 3) + oy;
        const float px = (float)(w - 1 + kk % 3) + ox;
        const float fy = floorf(py), fx = floorf(px);
        const int   y0 = (int)fy,   x0 = (int)fx;
        const float wy1 = py - fy, wx1 = px - fx;
        const float wy0 = 1.f - wy1, wx0 = 1.f - wx1;

        f32x4 ks = {0.f, 0.f, 0.f, 0.f};
        f32x4 vs = {0.f, 0.f, 0.f, 0.f};
        #define CORNER(yy, xx, wgt)                                               \
            if ((unsigned)(yy) < (unsigned)H_ && (unsigned)(xx) < (unsigned)W_) { \
                const int a = ((yy) * W_ + (xx)) * C_ + gc0;                      \
                const uint2 ku = *(const uint2*)(kp_b + a);                       \
                const uint2 vu = *(const uint2*)(vp_b + a);                       \
                const float wg = (wgt);                                           \
                ks[0] = fmaf(wg, b2f_lo(ku.x), ks[0]);                            \
                ks[1] = fmaf(wg, b2f_hi(ku.x), ks[1]);                            \
                ks[2] = fmaf(wg, b2f_lo(ku.y), ks[2]);                            \
                ks[3] = fmaf(wg, b2f_hi(ku.y), ks[3]);                            \
                vs[0] = fmaf(wg, b2f_lo(vu.x), vs[0]);                            \
                vs[1] = fmaf(wg, b2f_hi(vu.x), vs[1]);                            \
                vs[2] = fmaf(wg, b2f_lo(vu.y), vs[2]);                            \
                vs[3] = fmaf(wg, b2f_hi(vu.y), vs[3]);                            \
            }
        CORNER(y0,     x0,     wy0 * wx0)
        CORNER(y0,     x0 + 1, wy0 * wx1)
        CORNER(y0 + 1, x0,     wy1 * wx0)
        CORNER(y0 + 1, x0 + 1, wy1 * wx1)
        #undef CORNER

        float sc = q0 * ks[0];
        sc = fmaf(q1, ks[1], sc);
        sc = fmaf(q2, ks[2], sc);
        sc = fmaf(q3, ks[3], sc);
        sc += __shfl_xor(sc, 1, 4);
        sc += __shfl_xor(sc, 2, 4);
        score[kk] = sc * 0.25f;   // hd^-0.5
        vsamp[kk] = vs;
    }

    float m = score[0];
    #pragma unroll
    for (int kk = 1; kk < KPTS_; ++kk) m = fmaxf(m, score[kk]);
    float s = 0.f;
    #pragma unroll
    for (int kk = 0; kk < KPTS_; ++kk) { score[kk] = __expf(score[kk] - m); s += score[kk]; }
    const float inv = 1.f / s;

    f32x4 o = {0.f, 0.f, 0.f, 0.f};
    #pragma unroll
    for (int kk = 0; kk < KPTS_; ++kk) {
        o[0] = fmaf(score[kk], vsamp[kk][0], o[0]);
        o[1] = fmaf(score[kk], vsamp[kk][1], o[1]);
        o[2] = fmaf(score[kk], vsamp[kk][2], o[2]);
        o[3] = fmaf(score[kk], vsamp[kk][3], o[3]);
    }

    uint2 ob;
    ob.x = (uint)f2b(o[0] * inv) | ((uint)f2b(o[1] * inv) << 16);
    ob.y = (uint)f2b(o[2] * inv) | ((uint)f2b(o[3] * inv) << 16);
    *(uint2*)(aob + pix * C_ + gc0) = ob;
}

// ---------------------------------------------------------------------------
extern "C" void kernel_launch(void* const* d_in, const int* in_sizes, int n_in,
                              void* d_out, int out_size, void* d_ws, size_t ws_size,
                              hipStream_t stream)
{
    const float* q      = (const float*)d_in[0];
    const float* k      = (const float*)d_in[1];
    const float* v      = (const float*)d_in[2];
    const float* offset = (const float*)d_in[3];
    const float* Wq     = (const float*)d_in[4];
    const float* bq     = (const float*)d_in[5];
    const float* Wk     = (const float*)d_in[6];
    const float* bk     = (const float*)d_in[7];
    const float* Wv     = (const float*)d_in[8];
    const float* bv     = (const float*)d_in[9];
    const float* W1     = (const float*)d_in[10];
    const float* b1     = (const float*)d_in[11];
    const float* W2     = (const float*)d_in[12];
    const float* b2     = (const float*)d_in[13];

    ushort* Xcl = (ushort*)d_ws;               // [3][NPIX][192] bf16 packed inputs
    ushort* aob = Xcl;                         // alias: dead after proj
    ushort* qkv = Xcl + 3 * NPIX_ * C_;        // [3][NPIX][192] bf16 q/k/v proj
    ushort* Hb  = qkv + 3 * NPIX_ * C_;        // [NPIX][384] bf16
    ushort* Wt  = Hb + (size_t)NPIX_ * MLPH_;  // transposed bf16 weights
    ushort* W1T = Wt + 110592;
    ushort* W2T = Wt + 184320;

    pack_kernel<<<dim3(HW_ / 64, B_, 3), 256, 0, stream>>>(q, k, v, Xcl);
    wpack_kernel<<<1008, 256, 0, stream>>>(Wq, Wk, Wv, W1, W2, Wt);

    // q/k/v projections -> bf16 channels-last
    gemm_kernel<192, 0><<<dim3(NPIX_ / 128, 3, 3), 256, 0, stream>>>(
        Xcl, Wt, bq, bk, bv, qkv, nullptr, nullptr,
        NPIX_ * C_, C_ * C_, NPIX_ * C_);

    deform_attn_kernel<<<NPIX_ * G_ / 64, 256, 0, stream>>>(
        qkv, qkv + NPIX_ * C_, qkv + 2 * NPIX_ * C_, offset, aob);

    // MLP1: H = gelu(aob @ W1 + b1), bf16
    gemm_kernel<192, 1><<<dim3(NPIX_ / 128, 6, 1), 256, 0, stream>>>(
        aob, W1T, b1, b1, b1, Hb, nullptr, nullptr, 0, 0, 0);

    // MLP2: out = aob + (H @ W2 + b2), NCHW fp32
    gemm_kernel<384, 2><<<dim3(NPIX_ / 128, 3, 1), 256, 0, stream>>>(
        Hb, W2T, b2, b2, b2, nullptr, aob, (float*)d_out, 0, 0, 0);
}

// Round 4
// 200.650 us; speedup vs baseline: 4.3273x; 1.0785x over previous
//
#include <hip/hip_runtime.h>
#include <hip/hip_bf16.h>
#include <math.h>

#define B_    2
#define C_    192
#define H_    96
#define W_    96
#define HW_   (H_ * W_)          // 9216
#define NPIX_ (B_ * HW_)         // 18432
#define G_    12
#define CG_   16
#define KPTS_ 9
#define MLPH_ 384

typedef __attribute__((ext_vector_type(8))) short s16x8;
typedef __attribute__((ext_vector_type(4))) float f32x4;

__device__ __forceinline__ ushort f2b(float f) {
    __hip_bfloat16 h = __float2bfloat16(f);
    return *reinterpret_cast<ushort*>(&h);
}
__device__ __forceinline__ float b2f(ushort u) {
    return __uint_as_float(((uint)u) << 16);
}
__device__ __forceinline__ float b2f_lo(uint u) { return __uint_as_float(u << 16); }
__device__ __forceinline__ float b2f_hi(uint u) { return __uint_as_float(u & 0xffff0000u); }

#define GLOAD16(gp, lp)                                                          \
    __builtin_amdgcn_global_load_lds(                                            \
        (const __attribute__((address_space(1))) void*)(gp),                     \
        (__attribute__((address_space(3))) void*)(lp), 16, 0, 0)

// ---------------------------------------------------------------------------
// pack: q/k/v NCHW fp32 -> channels-last bf16 Xcl[3][NPIX][192]
// ---------------------------------------------------------------------------
__global__ __launch_bounds__(256) void pack_kernel(
    const float* __restrict__ q, const float* __restrict__ k,
    const float* __restrict__ v, ushort* __restrict__ Xcl)
{
    __shared__ ushort sm[64][196];   // stride 392B: 4-way write conflict, 8B-aligned
    const int t   = threadIdx.x;
    const int hw0 = blockIdx.x * 64;
    const int b   = blockIdx.y;
    const int z   = blockIdx.z;
    const float* X = (z == 0) ? q : (z == 1) ? k : v;

    const int hwl = t & 63;
    #pragma unroll 4
    for (int j = 0; j < 48; ++j) {
        const int c = (t >> 6) + j * 4;
        sm[hwl][c] = f2b(X[(b * C_ + c) * HW_ + hw0 + hwl]);
    }
    __syncthreads();
    #pragma unroll
    for (int jj = 0; jj < 12; ++jj) {
        const int idx = t + 256 * jj;        // < 64*48
        const int row = idx / 48, cq = idx - row * 48;
        const int pix = b * HW_ + hw0 + row;
        *(uint2*)&Xcl[((z * NPIX_) + pix) * C_ + cq * 4] = *(uint2*)&sm[row][cq * 4];
    }
}

// ---------------------------------------------------------------------------
// wpack: weights fp32 -> TRANSPOSED bf16 [N][K]
// ---------------------------------------------------------------------------
__global__ __launch_bounds__(256) void wpack_kernel(
    const float* __restrict__ Wq, const float* __restrict__ Wk,
    const float* __restrict__ Wv, const float* __restrict__ W1,
    const float* __restrict__ W2, ushort* __restrict__ Wt)
{
    const int i = blockIdx.x * 256 + threadIdx.x;
    if (i < 110592) {
        const int s = i / 36864, j = i - s * 36864;
        const float* src = (s == 0) ? Wq : (s == 1) ? Wk : Wv;
        const int d = j / 192, c = j - d * 192;
        Wt[i] = f2b(src[c * 192 + d]);
    } else if (i < 184320) {
        const int j = i - 110592, d = j / 192, c = j - d * 192;
        Wt[i] = f2b(W1[c * 384 + d]);
    } else if (i < 258048) {
        const int j = i - 184320, d = j / 384, c = j - d * 384;
        Wt[i] = f2b(W2[c * 192 + d]);
    }
}

// ---------------------------------------------------------------------------
// MFMA GEMM: O[M][N] = A[M][K] * BT[N][K]^T (+ epilogue)
//   BM=128 BN=64 BK=64, 4 waves (2m x 2n), 16x16x32 bf16 MFMA, dbuf LDS.
//   LDS chunk swizzle: physical chunk p at row r holds logical chunk p^(r&7).
//   EPI 0: bias -> bf16 channels-last (z selects q/k/v)
//   EPI 1: gelu(.+bias) -> bf16
//   EPI 2: .+bias+res(bf16) -> NCHW fp32 via LDS transpose
// ---------------------------------------------------------------------------
template<int KK>
__device__ __forceinline__ void stage_tiles64(const ushort* Az, const ushort* Bz,
                                              ushort* dst, int t, int m0, int n0, int kt)
{
    #pragma unroll
    for (int j = 0; j < 4; ++j) {
        const int q = t + 256 * j;
        const int r = q >> 3, p = q & 7;
        const int s = p ^ (r & 7);
        GLOAD16(Az + (size_t)(m0 + r) * KK + kt * 64 + s * 8, dst + q * 8);
    }
    #pragma unroll
    for (int j = 0; j < 2; ++j) {
        const int q = t + 256 * j;
        const int r = q >> 3, p = q & 7;
        const int s = p ^ (r & 7);
        GLOAD16(Bz + (size_t)(n0 + r) * KK + kt * 64 + s * 8, dst + 8192 + q * 8);
    }
}

template<int KK, int EPI>
__global__ __launch_bounds__(256) void gemm_kernel(
    const ushort* __restrict__ A,  const ushort* __restrict__ BT,
    const float* __restrict__ bias0, const float* __restrict__ bias1,
    const float* __restrict__ bias2,
    ushort* __restrict__ Ob,
    const ushort* __restrict__ res, float* __restrict__ Onchw,
    int zAstr, int zBstr, int zOstr)
{
    __shared__ char lds_raw[49152];          // 2 x (A 16KB + B 8KB); EPI2 reuses
    ushort* smem = (ushort*)lds_raw;

    const int t  = threadIdx.x;
    const int l  = t & 63;
    const int wid = t >> 6;
    const int wm = wid >> 1, wn = wid & 1;
    const int m0 = blockIdx.x * 128;
    const int n0 = blockIdx.y * 64;
    const int z  = blockIdx.z;
    const int Ntot = gridDim.y * 64;
    constexpr int NKT = KK / 64;

    const ushort* Az = A  + (size_t)z * zAstr;
    const ushort* Bz = BT + (size_t)z * zBstr;
    const float* bias = (z == 0) ? bias0 : (z == 1) ? bias1 : bias2;

    // fragment LDS offsets (ushort units)
    int aoff[4][2], boff[2][2];
    #pragma unroll
    for (int f = 0; f < 4; ++f) {
        const int r = wm * 64 + f * 16 + (l & 15);
        #pragma unroll
        for (int ks = 0; ks < 2; ++ks) {
            const int c = ks * 4 + (l >> 4);
            aoff[f][ks] = r * 64 + (c ^ (r & 7)) * 8;
        }
    }
    #pragma unroll
    for (int g = 0; g < 2; ++g) {
        const int r = wn * 32 + g * 16 + (l & 15);
        #pragma unroll
        for (int ks = 0; ks < 2; ++ks) {
            const int c = ks * 4 + (l >> 4);
            boff[g][ks] = 8192 + r * 64 + (c ^ (r & 7)) * 8;
        }
    }

    f32x4 acc[4][2] = {};

    stage_tiles64<KK>(Az, Bz, smem, t, m0, n0, 0);
    __syncthreads();

    for (int kt = 0; kt < NKT; ++kt) {
        if (kt + 1 < NKT)
            stage_tiles64<KK>(Az, Bz, smem + ((kt + 1) & 1) * 12288, t, m0, n0, kt + 1);

        const ushort* buf = smem + (kt & 1) * 12288;
        s16x8 af[4][2], bf[2][2];
        #pragma unroll
        for (int f = 0; f < 4; ++f)
            #pragma unroll
            for (int ks = 0; ks < 2; ++ks) af[f][ks] = *(const s16x8*)(buf + aoff[f][ks]);
        #pragma unroll
        for (int g = 0; g < 2; ++g)
            #pragma unroll
            for (int ks = 0; ks < 2; ++ks) bf[g][ks] = *(const s16x8*)(buf + boff[g][ks]);
        #pragma unroll
        for (int ks = 0; ks < 2; ++ks)
            #pragma unroll
            for (int f = 0; f < 4; ++f)
                #pragma unroll
                for (int g = 0; g < 2; ++g)
                    acc[f][g] = __builtin_amdgcn_mfma_f32_16x16x32_bf16(af[f][ks], bf[g][ks], acc[f][g], 0, 0, 0);
        __syncthreads();
    }

    const int rowg = l >> 4, ncol = l & 15;
    float bv[2];
    #pragma unroll
    for (int g = 0; g < 2; ++g) bv[g] = bias[n0 + wn * 32 + g * 16 + ncol];

    if (EPI == 0) {
        ushort* O = Ob + (size_t)z * zOstr;
        #pragma unroll
        for (int f = 0; f < 4; ++f)
            #pragma unroll
            for (int g = 0; g < 2; ++g)
                #pragma unroll
                for (int r = 0; r < 4; ++r) {
                    const int m = m0 + wm * 64 + f * 16 + rowg * 4 + r;
                    const int n = n0 + wn * 32 + g * 16 + ncol;
                    O[(size_t)m * Ntot + n] = f2b(acc[f][g][r] + bv[g]);
                }
    } else if (EPI == 1) {
        #pragma unroll
        for (int f = 0; f < 4; ++f)
            #pragma unroll
            for (int g = 0; g < 2; ++g)
                #pragma unroll
                for (int r = 0; r < 4; ++r) {
                    const int m = m0 + wm * 64 + f * 16 + rowg * 4 + r;
                    const int n = n0 + wn * 32 + g * 16 + ncol;
                    const float x = acc[f][g][r] + bv[g];
                    Ob[(size_t)m * Ntot + n] = f2b(0.5f * x * (1.f + erff(x * 0.70710678118f)));
                }
    } else {
        float* tsp = (float*)lds_raw;   // [64][132]
        #pragma unroll
        for (int f = 0; f < 4; ++f)
            #pragma unroll
            for (int g = 0; g < 2; ++g)
                #pragma unroll
                for (int r = 0; r < 4; ++r) {
                    const int ml = wm * 64 + f * 16 + rowg * 4 + r;
                    const int nl = wn * 32 + g * 16 + ncol;
                    const float rv = b2f(res[(size_t)(m0 + ml) * C_ + n0 + nl]);
                    tsp[nl * 132 + ml] = acc[f][g][r] + bv[g] + rv;
                }
        __syncthreads();
        const int b   = m0 / HW_;
        const int hw0 = m0 - b * HW_;
        #pragma unroll
        for (int jj = 0; jj < 8; ++jj) {
            const int i4 = t + 256 * jj;
            const int nn = i4 >> 5, mc = i4 & 31;
            float4 val = *(float4*)&tsp[nn * 132 + mc * 4];
            *(float4*)&Onchw[(size_t)b * C_ * HW_ + (size_t)(n0 + nn) * HW_ + hw0 + mc * 4] = val;
        }
    }
}

// ---------------------------------------------------------------------------
// deformable attention v3: 4 lanes per (pixel, group); lane owns 4 channels.
// All 36 corner addrs+weights precomputed (branch-free, OOB -> weight 0),
// 36 independent gathers per pass for latency hiding.
// ---------------------------------------------------------------------------
__global__ __launch_bounds__(256, 2) void deform_attn_kernel(
    const ushort* __restrict__ qp, const ushort* __restrict__ kp,
    const ushort* __restrict__ vp, const float* __restrict__ offset,
    ushort* __restrict__ aob)
{
    const int t   = threadIdx.x;
    const int bid = blockIdx.x;                    // 3456 blocks
    const int xb  = (bid & 7) * 432 + (bid >> 3);  // XCD-chunked swizzle
    const int pair = xb * 64 + (t >> 2);
    const int lane4 = t & 3;
    const int g   = pair % G_;
    const int pix = pair / G_;
    const int b   = pix / HW_;
    const int hw  = pix - b * HW_;
    const int h   = hw / W_;
    const int w   = hw - h * W_;
    const int gc0 = g * CG_ + lane4 * 4;

    // q: 4 channels
    float q0, q1, q2, q3;
    {
        uint2 qu = *(const uint2*)(qp + pix * C_ + gc0);
        q0 = b2f_lo(qu.x); q1 = b2f_hi(qu.x);
        q2 = b2f_lo(qu.y); q3 = b2f_hi(qu.y);
    }

    // offsets: lane l holds points l, l+4, l+8
    float offy[3] = {0.f, 0.f, 0.f}, offx[3] = {0.f, 0.f, 0.f};
    {
        const int obase = (b * (G_ * 2 * KPTS_) + g * (2 * KPTS_)) * HW_ + hw;
        #pragma unroll
        for (int s = 0; s < 3; ++s) {
            const int kk = lane4 + s * 4;
            if (kk < KPTS_) {
                offy[s] = offset[obase + (kk * 2) * HW_];
                offx[s] = offset[obase + (kk * 2 + 1) * HW_];
            }
        }
    }

    // all 36 corner addresses + masked weights, branch-free
    int   addr[KPTS_][4];
    float wgt[KPTS_][4];
    #pragma unroll
    for (int kk = 0; kk < KPTS_; ++kk) {
        const float oy = __shfl(offy[kk >> 2], kk & 3, 4);
        const float ox = __shfl(offx[kk >> 2], kk & 3, 4);
        const float py = (float)(h - 1 + kk / 3) + oy;
        const float px = (float)(w - 1 + kk % 3) + ox;
        const float fy = floorf(py), fx = floorf(px);
        const int   y0 = (int)fy,   x0 = (int)fx;
        const float wy1 = py - fy, wx1 = px - fx;
        const float wy0 = 1.f - wy1, wx0 = 1.f - wx1;

        const float wy0m = ((unsigned)y0       < (unsigned)H_) ? wy0 : 0.f;
        const float wy1m = ((unsigned)(y0 + 1) < (unsigned)H_) ? wy1 : 0.f;
        const float wx0m = ((unsigned)x0       < (unsigned)W_) ? wx0 : 0.f;
        const float wx1m = ((unsigned)(x0 + 1) < (unsigned)W_) ? wx1 : 0.f;
        const int yc0 = min(max(y0, 0), H_ - 1);
        const int yc1 = min(max(y0 + 1, 0), H_ - 1);
        const int xc0 = min(max(x0, 0), W_ - 1);
        const int xc1 = min(max(x0 + 1, 0), W_ - 1);

        addr[kk][0] = (yc0 * W_ + xc0) * C_ + gc0;  wgt[kk][0] = wy0m * wx0m;
        addr[kk][1] = (yc0 * W_ + xc1) * C_ + gc0;  wgt[kk][1] = wy0m * wx1m;
        addr[kk][2] = (yc1 * W_ + xc0) * C_ + gc0;  wgt[kk][2] = wy1m * wx0m;
        addr[kk][3] = (yc1 * W_ + xc1) * C_ + gc0;  wgt[kk][3] = wy1m * wx1m;
    }

    const ushort* kp_b = kp + (size_t)b * HW_ * C_;
    const ushort* vp_b = vp + (size_t)b * HW_ * C_;

    // ---- K-pass: 36 independent gathers, per-lane partial dots ----
    float score[KPTS_];
    #pragma unroll
    for (int kk = 0; kk < KPTS_; ++kk) {
        float s = 0.f;
        #pragma unroll
        for (int c = 0; c < 4; ++c) {
            const uint2 ku = *(const uint2*)(kp_b + addr[kk][c]);
            float d = q0 * b2f_lo(ku.x);
            d = fmaf(q1, b2f_hi(ku.x), d);
            d = fmaf(q2, b2f_lo(ku.y), d);
            d = fmaf(q3, b2f_hi(ku.y), d);
            s = fmaf(wgt[kk][c], d, s);
        }
        score[kk] = s;
    }
    // batched cross-lane reduction
    #pragma unroll
    for (int kk = 0; kk < KPTS_; ++kk) {
        float sc = score[kk];
        sc += __shfl_xor(sc, 1, 4);
        sc += __shfl_xor(sc, 2, 4);
        score[kk] = sc * 0.25f;   // hd^-0.5
    }

    // softmax over 9 points
    float m = score[0];
    #pragma unroll
    for (int kk = 1; kk < KPTS_; ++kk) m = fmaxf(m, score[kk]);
    float ssum = 0.f;
    #pragma unroll
    for (int kk = 0; kk < KPTS_; ++kk) { score[kk] = __expf(score[kk] - m); ssum += score[kk]; }
    const float inv = 1.f / ssum;

    // ---- V-pass: reuse addresses, prob folded into corner weight ----
    f32x4 o = {0.f, 0.f, 0.f, 0.f};
    #pragma unroll
    for (int kk = 0; kk < KPTS_; ++kk) {
        const float p = score[kk] * inv;
        #pragma unroll
        for (int c = 0; c < 4; ++c) {
            const float pw = p * wgt[kk][c];
            const uint2 vu = *(const uint2*)(vp_b + addr[kk][c]);
            o[0] = fmaf(pw, b2f_lo(vu.x), o[0]);
            o[1] = fmaf(pw, b2f_hi(vu.x), o[1]);
            o[2] = fmaf(pw, b2f_lo(vu.y), o[2]);
            o[3] = fmaf(pw, b2f_hi(vu.y), o[3]);
        }
    }

    uint2 ob;
    ob.x = (uint)f2b(o[0]) | ((uint)f2b(o[1]) << 16);
    ob.y = (uint)f2b(o[2]) | ((uint)f2b(o[3]) << 16);
    *(uint2*)(aob + pix * C_ + gc0) = ob;
}

// ---------------------------------------------------------------------------
extern "C" void kernel_launch(void* const* d_in, const int* in_sizes, int n_in,
                              void* d_out, int out_size, void* d_ws, size_t ws_size,
                              hipStream_t stream)
{
    const float* q      = (const float*)d_in[0];
    const float* k      = (const float*)d_in[1];
    const float* v      = (const float*)d_in[2];
    const float* offset = (const float*)d_in[3];
    const float* Wq     = (const float*)d_in[4];
    const float* bq     = (const float*)d_in[5];
    const float* Wk     = (const float*)d_in[6];
    const float* bk     = (const float*)d_in[7];
    const float* Wv     = (const float*)d_in[8];
    const float* bv     = (const float*)d_in[9];
    const float* W1     = (const float*)d_in[10];
    const float* b1     = (const float*)d_in[11];
    const float* W2     = (const float*)d_in[12];
    const float* b2     = (const float*)d_in[13];

    ushort* Xcl = (ushort*)d_ws;               // [3][NPIX][192] bf16 packed inputs
    ushort* aob = Xcl;                         // alias: dead after proj
    ushort* qkv = Xcl + 3 * NPIX_ * C_;        // [3][NPIX][192] bf16 q/k/v proj
    ushort* Hb  = qkv + 3 * NPIX_ * C_;        // [NPIX][384] bf16
    ushort* Wt  = Hb + (size_t)NPIX_ * MLPH_;  // transposed bf16 weights
    ushort* W1T = Wt + 110592;
    ushort* W2T = Wt + 184320;

    pack_kernel<<<dim3(HW_ / 64, B_, 3), 256, 0, stream>>>(q, k, v, Xcl);
    wpack_kernel<<<1008, 256, 0, stream>>>(Wq, Wk, Wv, W1, W2, Wt);

    // q/k/v projections -> bf16 channels-last
    gemm_kernel<192, 0><<<dim3(NPIX_ / 128, 3, 3), 256, 0, stream>>>(
        Xcl, Wt, bq, bk, bv, qkv, nullptr, nullptr,
        NPIX_ * C_, C_ * C_, NPIX_ * C_);

    deform_attn_kernel<<<NPIX_ * G_ / 64, 256, 0, stream>>>(
        qkv, qkv + NPIX_ * C_, qkv + 2 * NPIX_ * C_, offset, aob);

    // MLP1: H = gelu(aob @ W1 + b1), bf16
    gemm_kernel<192, 1><<<dim3(NPIX_ / 128, 6, 1), 256, 0, stream>>>(
        aob, W1T, b1, b1, b1, Hb, nullptr, nullptr, 0, 0, 0);

    // MLP2: out = aob + (H @ W2 + b2), NCHW fp32
    gemm_kernel<384, 2><<<dim3(NPIX_ / 128, 3, 1), 256, 0, stream>>>(
        Hb, W2T, b2, b2, b2, nullptr, aob, (float*)d_out, 0, 0, 0);
}